// Round 2
// baseline (182.739 us; speedup 1.0000x reference)
//
#include <hip/hip_runtime.h>
#include <cstdint>
#include <cstddef>

// out[64,197,768] = concat(cls, patchify(images[64,3,224,224]) @ W^T + b)
// Fully fused, zero-workspace: fp32 gather + bf16 convert in-register -> swizzled LDS -> MFMA.
// BM=64 x BN=128 -> 1176 blocks (4.6/CU). XOR swizzle (row&7)<<4 makes staging writes
// bank-uniform (round-1's 5.4M conflicts were write-side).
#define MTOT 12544   // 64*196
#define KTOT 768
#define NTOT 768

#define BM 64
#define BN 128
#define BK 64
#define NBLK_M 196   // 12544/64
#define NBLK_N 6     // 768/128
#define CLS_BLOCKS 48

typedef float  f32x4  __attribute__((ext_vector_type(4)));
typedef __bf16 bf16x8 __attribute__((ext_vector_type(8)));

__device__ __forceinline__ void pack8(const float4& a, const float4& b, bf16x8& o) {
  o[0]=(__bf16)a.x; o[1]=(__bf16)a.y; o[2]=(__bf16)a.z; o[3]=(__bf16)a.w;
  o[4]=(__bf16)b.x; o[5]=(__bf16)b.y; o[6]=(__bf16)b.z; o[7]=(__bf16)b.w;
}

__global__ __launch_bounds__(256, 4) void fused_kernel(
    const float* __restrict__ images, const float* __restrict__ Wm,
    const float* __restrict__ bias, const float* __restrict__ cls,
    float* __restrict__ out) {
  // Per-ks planes: As 64 rows x 64B, Bs 128 rows x 64B. Chunk addresses XOR'd by (row&7)<<4.
  __shared__ __bf16 As[2 * 64 * 32];    // 8 KB  (plane = 2048 elems = 4096 B)
  __shared__ __bf16 Bs[2 * 128 * 32];   // 16 KB (plane = 4096 elems = 8192 B)

  const int tid = threadIdx.x;
  const int bx  = blockIdx.x;

  // cls rows folded into first 48 blocks: 64*768 floats = 48*256 float4
  if (bx < CLS_BLOCKS) {
    const int t  = bx * 256 + tid;
    const int bb = t / 192, r = t - bb * 192;   // 192 float4 per row
    *(float4*)(out + (size_t)bb * 197 * 768 + r * 4) = *(const float4*)(cls + r * 4);
  }

  // mblk-inner: consecutive blocks share the W panel (L2); images L3-resident.
  const int mblk = bx % NBLK_M;
  const int nblk = bx / NBLK_M;
  const int m0 = mblk * BM, n0 = nblk * BN;
  const int wave = tid >> 6, lane = tid & 63;
  const int wm = (wave & 1) * 32;        // wave sub-tile 32(M) x 64(N)
  const int wn = (wave >> 1) * 64;
  const int lrow = lane & 15, lq = lane >> 4;

  // ---- A gather: 1 segment/thread = 16 contiguous floats (one 16px image-row piece).
  //      row = tid&63, jc = tid>>6; k_local = jc*16 + 0..15; ph = (kt&3)*4+jc, c = kt>>2.
  const int arow = tid & 63, ajc = tid >> 6;
  const float* pA;
  {
    const int m = m0 + arow;
    const int bb = m / 196, p = m - bb * 196;
    const int pi = p / 14, pj = p - pi * 14;
    pA = images + ((size_t)(bb * 3 * 224) + pi * 16 + ajc) * 224 + pj * 16;
  }
  __bf16* wA0;
  __bf16* wA1;
  {
    const int plane = (ajc >> 1) * 4096;           // bytes
    const int b0 = arow * 64 + (ajc & 1) * 32;     // bytes within plane
    const int sw = (arow & 7) << 4;
    wA0 = (__bf16*)((char*)As + plane + ((b0)      ^ sw));
    wA1 = (__bf16*)((char*)As + plane + ((b0 + 16) ^ sw));
  }

  // ---- B gather: W[768h][768k] fp32. 2 segments/thread of 16 floats.
  //      jc = tid&3 (4 threads cover 256B of one h-row), h = tid>>2 (+64 for s=1).
  const int bjc = tid & 3, bh = tid >> 2;
  const float* pB[2];
  __bf16* wB[2][2];
#pragma unroll
  for (int s = 0; s < 2; ++s) {
    const int h = bh + s * 64;
    pB[s] = Wm + (size_t)(n0 + h) * 768 + bjc * 16;
    const int plane = (bjc >> 1) * 8192;
    const int b0 = h * 64 + (bjc & 1) * 32;
    const int sw = (h & 7) << 4;
    wB[s][0] = (__bf16*)((char*)Bs + plane + ((b0)      ^ sw));
    wB[s][1] = (__bf16*)((char*)Bs + plane + ((b0 + 16) ^ sw));
  }

  // ---- MFMA fragment read offsets (elems), loop-invariant, same XOR involution.
  int aoff[2], boff[4];
#pragma unroll
  for (int i = 0; i < 2; ++i) {
    const int r = wm + i * 16 + lrow;
    aoff[i] = ((r * 64 + lq * 16) ^ ((r & 7) << 4)) >> 1;
  }
#pragma unroll
  for (int j = 0; j < 4; ++j) {
    const int r = wn + j * 16 + lrow;
    boff[j] = ((r * 64 + lq * 16) ^ ((r & 7) << 4)) >> 1;
  }

  f32x4 acc[2][4] = {};
  float4 ra[4], rb[2][4];

  // prologue: loads for kt=0
#pragma unroll
  for (int q = 0; q < 4; ++q) ra[q] = *(const float4*)(pA + q * 4);
#pragma unroll
  for (int s = 0; s < 2; ++s)
#pragma unroll
    for (int q = 0; q < 4; ++q) rb[s][q] = *(const float4*)(pB[s] + q * 4);

  for (int kt = 0; kt < KTOT / BK; ++kt) {   // 12 iterations
    // convert + swizzled LDS write
    {
      bf16x8 o0, o1;
      pack8(ra[0], ra[1], o0); pack8(ra[2], ra[3], o1);
      *(bf16x8*)wA0 = o0; *(bf16x8*)wA1 = o1;
    }
#pragma unroll
    for (int s = 0; s < 2; ++s) {
      bf16x8 o0, o1;
      pack8(rb[s][0], rb[s][1], o0); pack8(rb[s][2], rb[s][3], o1);
      *(bf16x8*)wB[s][0] = o0; *(bf16x8*)wB[s][1] = o1;
    }
    __syncthreads();   // tiles visible

    // T14: issue next tile's global loads now; MFMA phase hides the latency
    const int dA = ((kt & 3) == 3) ? 47488 : 896;  // +4 image rows, or channel-cross
    pA += dA; pB[0] += BK; pB[1] += BK;
    if (kt < KTOT / BK - 1) {
#pragma unroll
      for (int q = 0; q < 4; ++q) ra[q] = *(const float4*)(pA + q * 4);
#pragma unroll
      for (int s = 0; s < 2; ++s)
#pragma unroll
        for (int q = 0; q < 4; ++q) rb[s][q] = *(const float4*)(pB[s] + q * 4);
    }

#pragma unroll
    for (int ks = 0; ks < 2; ++ks) {
      bf16x8 af[2], bf[4];
#pragma unroll
      for (int i = 0; i < 2; ++i)
        af[i] = *(const bf16x8*)&As[ks * 2048 + aoff[i]];
#pragma unroll
      for (int j = 0; j < 4; ++j)
        bf[j] = *(const bf16x8*)&Bs[ks * 4096 + boff[j]];
#pragma unroll
      for (int i = 0; i < 2; ++i)
#pragma unroll
        for (int j = 0; j < 4; ++j)
          acc[i][j] = __builtin_amdgcn_mfma_f32_16x16x32_bf16(af[i], bf[j], acc[i][j], 0, 0, 0);
    }
    __syncthreads();   // protect LDS from next kt's writes
  }

  // Epilogue: C/D layout col=lane&15, row=(lane>>4)*4+r (round-0-verified convention)
#pragma unroll
  for (int j = 0; j < 4; ++j) {
    const int h  = n0 + wn + j * 16 + lrow;
    const float bv = bias[h];
#pragma unroll
    for (int i = 0; i < 2; ++i) {
      const int mb = m0 + wm + i * 16 + lq * 4;
#pragma unroll
      for (int r = 0; r < 4; ++r) {
        const int m  = mb + r;
        const int bb = m / 196, p = m - bb * 196;
        out[(size_t)(bb * 197 + 1 + p) * 768 + h] = acc[i][j][r] + bv;
      }
    }
  }
}

extern "C" void kernel_launch(void* const* d_in, const int* in_sizes, int n_in,
                              void* d_out, int out_size, void* d_ws, size_t ws_size,
                              hipStream_t stream) {
  const float* images = (const float*)d_in[0];  // [64,3,224,224]
  const float* Wm     = (const float*)d_in[1];  // [768,768]
  const float* b      = (const float*)d_in[2];  // [768]
  const float* cls    = (const float*)d_in[3];  // [1,768]
  float* out = (float*)d_out;                   // [64,197,768]
  (void)in_sizes; (void)n_in; (void)out_size; (void)d_ws; (void)ws_size;

  fused_kernel<<<NBLK_M * NBLK_N, 256, 0, stream>>>(images, Wm, b, cls, out);
}

// Round 4
// 137.813 us; speedup vs baseline: 1.3260x; 1.3260x over previous
//
#include <hip/hip_runtime.h>
#include <cstdint>
#include <cstddef>

// out[64,197,768] = concat(cls, patchify(images[64,3,224,224]) @ W^T + b)
// Fully fused, zero-workspace. v3: COALESCED reg-staging (every global load = 16 lines/wave,
// the minimum), BM=BN=128 (4x4 acc, 0.5 ds_read_b128/MFMA), XOR-swizzled LDS, T14 prefetch.
// (Resubmission of round-3 source — bench never ran: GPUAcquisitionTimeout.)
#define MTOT 12544
#define KTOT 768
#define BM 128
#define BN 128
#define BK 64
#define NBLK_M 98    // 12544/128
#define NBLK_N 6     // 768/128
#define CLS_BLOCKS 48

typedef float  f32x4  __attribute__((ext_vector_type(4)));
typedef __bf16 bf16x4 __attribute__((ext_vector_type(4)));
typedef __bf16 bf16x8 __attribute__((ext_vector_type(8)));

__device__ __forceinline__ bf16x4 cvt4(const float4 v) {
  bf16x4 o;
  o[0]=(__bf16)v.x; o[1]=(__bf16)v.y; o[2]=(__bf16)v.z; o[3]=(__bf16)v.w;
  return o;
}

__global__ __launch_bounds__(256, 2) void fused_kernel(
    const float* __restrict__ images, const float* __restrict__ Wm,
    const float* __restrict__ bias, const float* __restrict__ cls,
    float* __restrict__ out) {
  // LDS byte layout: row*128 + (kbyte ^ ((row&7)<<4)), kbyte = k_local*2. 16KB each.
  __shared__ __bf16 As[BM * BK];
  __shared__ __bf16 Bs[BN * BK];

  const int tid = threadIdx.x;
  const int bx  = blockIdx.x;

  // cls rows folded into first 48 blocks
  if (bx < CLS_BLOCKS) {
    const int t  = bx * 256 + tid;
    const int bb = t / 192, r = t - bb * 192;
    *(float4*)(out + (size_t)bb * 197 * 768 + r * 4) = *(const float4*)(cls + r * 4);
  }

  // nblk-inner: 6 consecutive blocks share one A tile (L2 reuse -> images ~1x from HBM)
  const int mblk = bx / NBLK_N;
  const int nblk = bx - mblk * NBLK_N;
  const int m0 = mblk * BM, n0 = nblk * BN;
  const int wave = tid >> 6, lane = tid & 63;
  const int wm = (wave & 1) * 64, wn = (wave >> 1) * 64;
  const int lrow = lane & 15, lq = lane >> 4;

  // ---- A global map, instr s=0..7: m = m0+(s&1)*64+(t>>2), ph = s>>1, chunk f = t&3.
  //      4-lane groups read one full aligned 64B line; lines contiguous across m. Coalesced.
  const float* baseA[2];
#pragma unroll
  for (int r = 0; r < 2; ++r) {
    const int m = m0 + r * 64 + (tid >> 2);
    const int bb = m / 196, p = m - bb * 196;
    const int pi = p / 14, pj = p - pi * 14;
    baseA[r] = images + ((size_t)(bb * 672 + pi * 16)) * 224 + pj * 16 + (tid & 3) * 4;
  }
  // ---- B global map, instr s=0..7: h = n0+s*16+(t>>4), chunk f16 = t&15.
  //      16 lanes cover one contiguous 256B row-piece. Coalesced.
  const float* baseB = Wm + (size_t)(n0 + (tid >> 4)) * 768 + (tid & 15) * 4;

  // ---- LDS write addrs (bytes). A: k_local=(s>>1)*16+(t&3)*4; B: k_local=(t&15)*4.
  const int xa = ((tid >> 2) & 7) << 4;
  int wA[4];
#pragma unroll
  for (int jj = 0; jj < 4; ++jj)
    wA[jj] = (tid >> 2) * 128 + (((jj * 32) | ((tid & 3) * 8)) ^ xa);
  const int xb = ((tid >> 4) & 7) << 4;
  const int wB = (tid >> 4) * 128 + (((tid & 15) * 8) ^ xb);

  // ---- MFMA read offsets. (r&7)==(lrow&7) independent of i/j -> +i*2048 imm-folds.
  const int xr = (lrow & 7) << 4;
  int aoff[2], boff[2];
#pragma unroll
  for (int ks = 0; ks < 2; ++ks) {
    const int ko = (ks * 64 + lq * 16) ^ xr;
    aoff[ks] = (wm + lrow) * 128 + ko;
    boff[ks] = (wn + lrow) * 128 + ko;
  }

  f32x4 acc[4][4] = {};
  float4 ra[8], rb[8];

#pragma unroll
  for (int s = 0; s < 8; ++s) {
    ra[s] = *(const float4*)(baseA[s & 1] + (s >> 1) * 224);
    rb[s] = *(const float4*)(baseB + s * (16 * 768));
  }

  char* AsB = (char*)As;
  char* BsB = (char*)Bs;

  for (int kt = 0; kt < KTOT / BK; ++kt) {   // 12 iterations
    // convert + swizzled LDS write (consumes this kt's prefetch)
#pragma unroll
    for (int s = 0; s < 8; ++s)
      *(bf16x4*)(AsB + wA[s >> 1] + (s & 1) * 8192) = cvt4(ra[s]);
#pragma unroll
    for (int s = 0; s < 8; ++s)
      *(bf16x4*)(BsB + wB + s * 2048) = cvt4(rb[s]);
    __syncthreads();   // tiles visible

    // T14: issue next tile's loads; MFMA phase hides the latency
    const int dA = ((kt & 3) == 3) ? 47488 : 896;  // +4 image rows, or channel-cross
    baseA[0] += dA; baseA[1] += dA; baseB += BK;
    if (kt < KTOT / BK - 1) {
#pragma unroll
      for (int s = 0; s < 8; ++s) {
        ra[s] = *(const float4*)(baseA[s & 1] + (s >> 1) * 224);
        rb[s] = *(const float4*)(baseB + s * (16 * 768));
      }
    }

#pragma unroll
    for (int ks = 0; ks < 2; ++ks) {
      bf16x8 af[4], bf[4];
#pragma unroll
      for (int i = 0; i < 4; ++i) af[i] = *(const bf16x8*)(AsB + aoff[ks] + i * 2048);
#pragma unroll
      for (int j = 0; j < 4; ++j) bf[j] = *(const bf16x8*)(BsB + boff[ks] + j * 2048);
#pragma unroll
      for (int i = 0; i < 4; ++i)
#pragma unroll
        for (int j = 0; j < 4; ++j)
          acc[i][j] = __builtin_amdgcn_mfma_f32_16x16x32_bf16(af[i], bf[j], acc[i][j], 0, 0, 0);
    }
    __syncthreads();   // protect LDS from next kt's writes
  }

  // Epilogue: C/D layout col=lane&15, row=(lane>>4)*4+r (verified convention, rounds 0-2)
#pragma unroll
  for (int j = 0; j < 4; ++j) {
    const int h  = n0 + wn + j * 16 + lrow;
    const float bv = bias[h];
#pragma unroll
    for (int i = 0; i < 4; ++i) {
      const int mb = m0 + wm + i * 16 + lq * 4;
#pragma unroll
      for (int r = 0; r < 4; ++r) {
        const int m  = mb + r;
        const int bb = m / 196, p = m - bb * 196;
        out[(size_t)(bb * 197 + 1 + p) * 768 + h] = acc[i][j][r] + bv;
      }
    }
  }
}

extern "C" void kernel_launch(void* const* d_in, const int* in_sizes, int n_in,
                              void* d_out, int out_size, void* d_ws, size_t ws_size,
                              hipStream_t stream) {
  const float* images = (const float*)d_in[0];  // [64,3,224,224]
  const float* Wm     = (const float*)d_in[1];  // [768,768]
  const float* b      = (const float*)d_in[2];  // [768]
  const float* cls    = (const float*)d_in[3];  // [1,768]
  float* out = (float*)d_out;                   // [64,197,768]
  (void)in_sizes; (void)n_in; (void)out_size; (void)d_ws; (void)ws_size;

  fused_kernel<<<NBLK_M * NBLK_N, 256, 0, stream>>>(images, Wm, b, cls, out);
}

// Round 5
// 112.275 us; speedup vs baseline: 1.6276x; 1.2275x over previous
//
#include <hip/hip_runtime.h>
#include <cstdint>
#include <cstddef>

// out[64,197,768] = concat(cls, patchify(images[64,3,224,224]) @ W^T + b)
// v4 = round-0 verified two-kernel structure (prep fp32->bf16 + gemm global_load_lds)
//      + XCD-bijective block swizzle in gemm (1176 = 8*147): the 6 blocks sharing an
//      A-tile now run on ONE XCD -> A/W staging hits L2 instead of L3/HBM every kt.
#define MTOT 12544   // 64*196 GEMM rows
#define KTOT 768
#define NTOT 768

typedef float  f32x4  __attribute__((ext_vector_type(4)));
typedef __bf16 bf16x8 __attribute__((ext_vector_type(8)));

// ---------------- Prep: coalesced fp32->bf16 convert (images, W) + cls rows ----------------
#define IMG_ELEMS (64*3*224*224)       // 9,633,792
#define W_ELEMS   (768*768)            // 589,824
#define A_BLOCKS  (IMG_ELEMS/8/256)    // 4704
#define W_BLOCKS  (W_ELEMS/8/256)      // 288
#define CLS_BLOCKS 48                  // 64*768 floats / 4 / 256

__global__ __launch_bounds__(256) void prep_kernel(
    const float* __restrict__ images, const float* __restrict__ Wm,
    const float* __restrict__ cls, float* __restrict__ out,
    __bf16* __restrict__ imgb, __bf16* __restrict__ Wb) {
  const int bid = blockIdx.x, tid = threadIdx.x;
  if (bid < A_BLOCKS) {
    const size_t q = (size_t)bid * 256 + tid;
    const float4 v0 = *(const float4*)(images + q * 8);
    const float4 v1 = *(const float4*)(images + q * 8 + 4);
    bf16x8 o;
    o[0]=(__bf16)v0.x; o[1]=(__bf16)v0.y; o[2]=(__bf16)v0.z; o[3]=(__bf16)v0.w;
    o[4]=(__bf16)v1.x; o[5]=(__bf16)v1.y; o[6]=(__bf16)v1.z; o[7]=(__bf16)v1.w;
    *(bf16x8*)(imgb + q * 8) = o;
  } else if (bid < A_BLOCKS + W_BLOCKS) {
    const size_t q = (size_t)(bid - A_BLOCKS) * 256 + tid;
    const float4 v0 = *(const float4*)(Wm + q * 8);
    const float4 v1 = *(const float4*)(Wm + q * 8 + 4);
    bf16x8 o;
    o[0]=(__bf16)v0.x; o[1]=(__bf16)v0.y; o[2]=(__bf16)v0.z; o[3]=(__bf16)v0.w;
    o[4]=(__bf16)v1.x; o[5]=(__bf16)v1.y; o[6]=(__bf16)v1.z; o[7]=(__bf16)v1.w;
    *(bf16x8*)(Wb + q * 8) = o;
  } else {
    const int t  = (bid - A_BLOCKS - W_BLOCKS) * 256 + tid;
    const int bb = t / 192;             // 192 float4 per row
    const int r  = t - bb * 192;
    *(float4*)(out + (size_t)bb * 197 * 768 + r * 4) = *(const float4*)(cls + r * 4);
  }
}

// ---------------- GEMM: fused patchify-gather + MFMA ----------------
// BM=64, BN=128, BK=64 -> grid 196*6 = 1176 blocks (4.6/CU, 92% balance).
// LDS layout [kstep][row][32] keeps 64B row stride (conflict-optimal b128 reads).
#define BM 64
#define BN 128
#define BK 64
#define NBLK_N 6    // 768/128
#define NWG   1176  // (MTOT/BM)*NBLK_N = 8 * 147 exactly
#define WG_PER_XCD 147

__device__ __forceinline__ void gload_lds16(const void* g, void* l) {
  __builtin_amdgcn_global_load_lds((__attribute__((address_space(1))) void*)(g),
                                   (__attribute__((address_space(3))) void*)(l),
                                   16, 0, 0);
}

__global__ __launch_bounds__(256) void gemm_kernel(
    const __bf16* __restrict__ imgb, const __bf16* __restrict__ Wb,
    const float* __restrict__ bias, float* __restrict__ out) {
  __shared__ __bf16 As[2 * 64 * 32];   // 8 KB: [kstep][row 0..63][k 0..31]
  __shared__ __bf16 Bs[2 * 128 * 32];  // 16 KB

  const int tid  = threadIdx.x;
  // XCD-bijective swizzle: dispatch round-robins blockIdx across 8 XCDs; remap so each
  // XCD owns a CONTIGUOUS range of logical tiles. 1176 = 8*147 -> exact.
  const int bx   = blockIdx.x;
  const int wgid = (bx & 7) * WG_PER_XCD + (bx >> 3);
  // nblk-inner: 6 consecutive wgid (same XCD) share one A-tile; W (2.36 MB) L2-resident.
  const int mblk = wgid / NBLK_N;
  const int nblk = wgid - mblk * NBLK_N;
  const int m0 = mblk * BM;
  const int n0 = nblk * BN;
  const int wave = tid >> 6, lane = tid & 63;
  const int wm = (wave & 1) * 32;   // wave sub-tile 32(M) x 64(N)
  const int wn = (wave >> 1) * 64;
  const int lrow = lane & 15, lq = lane >> 4;

  f32x4 acc[2][4] = {};

  // A staging: 512 16B chunks; chunk c = wave*128 + s*64 + lane
  //   kstep=c>>8, row=(c&255)>>2, jc=c&3 -> k_in_tile = kstep*32+jc*8
  //   global: patchify gather; per-kt advance is a wave-uniform elem delta.
  const __bf16* pA[2];
#pragma unroll
  for (int s = 0; s < 2; ++s) {
    const int c = wave * 128 + s * 64 + lane;
    const int kstep = c >> 8, rem = c & 255;
    const int row = rem >> 2, jc = rem & 3;
    const int m = m0 + row;
    const int bb = m / 196, p = m - bb * 196;
    const int pi = p / 14, pj = p - pi * 14;
    const int ph_off = kstep * 2 + (jc >> 1);
    const int pw_off = (jc & 1) * 8;
    const size_t e = ((size_t)(bb * 3 * 224 + pi * 16 + ph_off)) * 224 + pj * 16 + pw_off;
    pA[s] = imgb + e;
  }
  // B staging: 1024 chunks; c = wave*256 + s*64 + lane
  const __bf16* pB[4];
#pragma unroll
  for (int s = 0; s < 4; ++s) {
    const int c = wave * 256 + s * 64 + lane;
    const int kstep = c >> 9, rem = c & 511;
    const int h = rem >> 2, jc = rem & 3;
    pB[s] = Wb + (size_t)(n0 + h) * 768 + kstep * 32 + jc * 8;
  }
  __bf16* lA[2];
  __bf16* lB[4];
#pragma unroll
  for (int s = 0; s < 2; ++s) lA[s] = As + (wave * 128 + s * 64) * 8;  // chunk*8 elems
#pragma unroll
  for (int s = 0; s < 4; ++s) lB[s] = Bs + (wave * 256 + s * 64) * 8;

  for (int kt = 0; kt < KTOT / BK; ++kt) {   // 12 iterations
#pragma unroll
    for (int s = 0; s < 2; ++s) gload_lds16(pA[s], lA[s]);
#pragma unroll
    for (int s = 0; s < 4; ++s) gload_lds16(pB[s], lB[s]);
    // advance: +4 image rows within channel; at channel crossing +50176-2688 elems
    const int dA = ((kt & 3) == 3) ? 47488 : 896;
    pA[0] += dA; pA[1] += dA;
    pB[0] += BK; pB[1] += BK; pB[2] += BK; pB[3] += BK;
    __syncthreads();   // drain vmcnt -> tiles complete

#pragma unroll
    for (int ks = 0; ks < 2; ++ks) {
      bf16x8 af[2], bf[4];
#pragma unroll
      for (int i = 0; i < 2; ++i)
        af[i] = *(const bf16x8*)&As[ks * 2048 + (wm + i * 16 + lrow) * 32 + lq * 8];
#pragma unroll
      for (int j = 0; j < 4; ++j)
        bf[j] = *(const bf16x8*)&Bs[ks * 4096 + (wn + j * 16 + lrow) * 32 + lq * 8];
#pragma unroll
      for (int i = 0; i < 2; ++i)
#pragma unroll
        for (int j = 0; j < 4; ++j)
          acc[i][j] = __builtin_amdgcn_mfma_f32_16x16x32_bf16(af[i], bf[j], acc[i][j], 0, 0, 0);
    }
    __syncthreads();
  }

  // Epilogue: C/D layout col=lane&15, row=(lane>>4)*4+r (round-0-verified convention)
#pragma unroll
  for (int j = 0; j < 4; ++j) {
    const int h  = n0 + wn + j * 16 + lrow;
    const float bv = bias[h];
#pragma unroll
    for (int i = 0; i < 2; ++i) {
      const int mb = m0 + wm + i * 16 + lq * 4;
#pragma unroll
      for (int r = 0; r < 4; ++r) {
        const int m  = mb + r;
        const int bb = m / 196, p = m - bb * 196;
        out[(size_t)(bb * 197 + 1 + p) * 768 + h] = acc[i][j][r] + bv;
      }
    }
  }
}

extern "C" void kernel_launch(void* const* d_in, const int* in_sizes, int n_in,
                              void* d_out, int out_size, void* d_ws, size_t ws_size,
                              hipStream_t stream) {
  const float* images = (const float*)d_in[0];  // [64,3,224,224]
  const float* Wm     = (const float*)d_in[1];  // [768,768]
  const float* b      = (const float*)d_in[2];  // [768]
  const float* cls    = (const float*)d_in[3];  // [1,768]
  float* out = (float*)d_out;                   // [64,197,768]

  __bf16* imgb = (__bf16*)d_ws;                   // 19.27 MB
  __bf16* Wb   = imgb + (size_t)IMG_ELEMS;        // 1.18 MB
  (void)in_sizes; (void)n_in; (void)out_size; (void)ws_size;

  prep_kernel<<<A_BLOCKS + W_BLOCKS + CLS_BLOCKS, 256, 0, stream>>>(
      images, Wm, cls, out, imgb, Wb);
  gemm_kernel<<<NWG, 256, 0, stream>>>(imgb, Wb, b, out);
}